// Round 5
// baseline (246.996 us; speedup 1.0000x reference)
//
#include <hip/hip_runtime.h>
#include <math.h>

#define BGRAPHS 256
#define NNODES  1024
#define CCH     64
#define NEDGE   4194304
#define KKEEP   512

typedef unsigned long long u64;
typedef unsigned int u32;
typedef unsigned short u16;
typedef float  f32x4 __attribute__((ext_vector_type(4)));
typedef int    i32x4 __attribute__((ext_vector_type(4)));

// Output layout (flat float32 elements)
#define OFF_XP   0
#define OFF_EI0  8388608
#define OFF_EI1  (8388608 + NEDGE)
#define OFF_EA   16777216
#define OFF_BP   20971520
#define OFF_SC   21102592
#define OFF_PM   21364736
#define OFF_MSK  21495808

#define FUSED_BLOCKS 2048       // 524288 threads: 8 edges + 4 xp-float4s each
#define GTHREADS     524288
#define BMWORDS      8192       // 256K nodes / 32 = 8192 u32 = 32 KB

// ------------- Kernel A: fused score + rank-by-counting top-k + bitmap -------------
// 256 blocks x 1024 threads (1 graph/block). Score phase: 16 independent
// float4 loads/thread (deep MLP, streams x at ~peak even at 16 waves/CU).
// Rank core is R3-verbatim: wave bitonic sort (no barriers) + ONE barrier +
// 15 independent binary searches over u64 keys in LDS. No else-write of
// 0xFFFF sentinels: bitmap gates every table16 read downstream.
__device__ __forceinline__ u64 cmpex(u64 key, int j, bool dir, int lane) {
    u64 o = (u64)__shfl_xor((long long)key, j, 64);
    bool lower = ((lane & j) == 0);
    u64 mn = key < o ? key : o;
    u64 mx = key < o ? o : key;
    return (dir == lower) ? mn : mx;
}

__global__ __launch_bounds__(1024) void score_rank_kernel(
    const float* __restrict__ x, const float* __restrict__ w,
    const float* __restrict__ bias,
    float* __restrict__ sco, float* __restrict__ pmo, float* __restrict__ bpo,
    u16* __restrict__ table16, u16* __restrict__ src16,
    u32* __restrict__ bitmap)
{
    __shared__ float s_w[CCH];
    __shared__ u64 s_key[NNODES];
    __shared__ u32 s_bm[32];
    const int b = blockIdx.x;
    const int tid = threadIdx.x;
    const int lane = tid & 63;
    if (tid < CCH) s_w[tid] = w[tid];
    if (tid < 32) s_bm[tid] = 0u;
    __syncthreads();

    // ---- score phase ----
    double n2 = 0.0;
    #pragma unroll
    for (int k = 0; k < CCH; ++k) { double v = (double)s_w[k]; n2 += v * v; }
    const float nrm = (float)sqrt(n2);
    const float bv = bias[0];

    const int node = (b << 10) + tid;
    const f32x4* x4 = (const f32x4*)x;
    double acc = 0.0;
    #pragma unroll
    for (int k = 0; k < 16; ++k) {
        f32x4 xv = x4[node * 16 + k];
        acc += (double)xv.x * (double)s_w[4 * k + 0];
        acc += (double)xv.y * (double)s_w[4 * k + 1];
        acc += (double)xv.z * (double)s_w[4 * k + 2];
        acc += (double)xv.w * (double)s_w[4 * k + 3];
    }
    const float score = ((float)acc + bv) / nrm;
    __builtin_nontemporal_store(score, &sco[node]);

    // ---- rank phase (R3 core) ----
    // key: descending score (primary), ascending index (secondary) -> ascending u64
    u32 u = __float_as_uint(score);
    u32 mu = u ^ (u32)(((int)u >> 31) | 0x80000000);
    u64 key = ((u64)(~mu) << 32) | (u32)tid;

    // in-wave bitonic sort: 64 keys ascending across the wave's lanes
    #pragma unroll
    for (int k = 2; k <= 64; k <<= 1) {
        bool dir = ((lane & k) == 0);
        for (int j = k >> 1; j > 0; j >>= 1)
            key = cmpex(key, j, dir, lane);
    }
    s_key[tid] = key;
    __syncthreads();

    // global rank: lane = count of smaller keys in own chunk (sorted, unique)
    const int mychunk = tid >> 6;      // wave-uniform
    int rank = lane;
    #pragma unroll
    for (int c = 0; c < 16; ++c) {
        if (c == mychunk) continue;    // wave-uniform branch
        const u64* base = &s_key[c << 6];
        int pos = 0;
        #pragma unroll
        for (int s = 32; s > 0; s >>= 1)
            pos += (base[pos + s - 1] < key) ? s : 0;
        pos += (base[pos] < key) ? 1 : 0;   // lower_bound in [0,64]
        rank += pos;
    }

    const int lidx = (int)(u32)key;
    const int g = (b << 10) + lidx;
    if (rank < KKEEP) {
        pmo[b * KKEEP + rank] = (float)g;
        bpo[b * KKEEP + rank] = (float)b;   // batch[g] == b by construction
        table16[g] = (u16)rank;             // local rank 0..511
        src16[b * KKEEP + rank] = (u16)lidx;
        atomicOr(&s_bm[lidx >> 5], 1u << (lidx & 31));
    }
    __syncthreads();
    if (tid < 32) bitmap[(b << 5) + tid] = s_bm[tid];
}

// ---------------- Kernel C: fused edge-filter + x_p gather ----------------
// Validity bitmap (32 KB) staged in LDS; table16 gathered ONLY for edges
// whose both endpoints survive (~25%) — masked lanes collapse to a single
// broadcast line (index 0). Cuts random L2 gather-lines ~4x.
__global__ __launch_bounds__(256) void edge_gather_kernel(
    const int* __restrict__ ei, const float* __restrict__ ea,
    const u16* __restrict__ table16, const u32* __restrict__ bitmap,
    const float* __restrict__ x, const u16* __restrict__ src16,
    float* __restrict__ ei0o, float* __restrict__ ei1o,
    float* __restrict__ eao, float* __restrict__ msk,
    float* __restrict__ xp)
{
    __shared__ u32 s_bm[BMWORDS];
    const int tid = threadIdx.x;
    const int gt = blockIdx.x * 256 + tid;      // 0..GTHREADS-1
    const int i0 = blockIdx.x * 512 + tid;      // int4 slot A (4 edges)
    const int i1 = i0 + 256;                    // int4 slot B

    // stage validity bitmap (32 KB) — coalesced, L2/L3-hot
    {
        const i32x4* bm4 = (const i32x4*)bitmap;
        i32x4* sb4 = (i32x4*)s_bm;
        #pragma unroll
        for (int i = 0; i < 8; ++i)
            sb4[tid + 256 * i] = bm4[tid + 256 * i];
    }

    const i32x4* s4p = (const i32x4*)ei;
    const i32x4* d4p = (const i32x4*)(ei + NEDGE);
    const f32x4* a4p = (const f32x4*)ea;
    const f32x4* x4  = (const f32x4*)x;

    // --- round 1: independent loads (6 edge streams + 4 src16) ---
    i32x4 sA = __builtin_nontemporal_load(&s4p[i0]);
    i32x4 sB = __builtin_nontemporal_load(&s4p[i1]);
    i32x4 dA = __builtin_nontemporal_load(&d4p[i0]);
    i32x4 dB = __builtin_nontemporal_load(&d4p[i1]);
    f32x4 aA = __builtin_nontemporal_load(&a4p[i0]);
    f32x4 aB = __builtin_nontemporal_load(&a4p[i1]);

    int rowv[4], colv[4], srcv[4];
    #pragma unroll
    for (int p = 0; p < 4; ++p) {
        int elem = gt + p * GTHREADS;
        rowv[p] = elem >> 4;
        colv[p] = elem & 15;
        srcv[p] = (int)src16[rowv[p]];    // 16 lanes share a row -> near-broadcast
    }

    // --- round 3 (moved up): x_p source rows, independent of edge data ---
    f32x4 xv[4];
    #pragma unroll
    for (int p = 0; p < 4; ++p) {
        int bb = rowv[p] >> 9;
        xv[p] = x4[((bb << 10) + srcv[p]) * 16 + colv[p]];
    }

    __syncthreads();   // bitmap ready

    // --- round 2: bitmap masks (LDS), then predicated table gathers ---
    int mAi[4], mBi[4];
    #pragma unroll
    for (int q = 0; q < 4; ++q) {
        int is = ((const int*)&sA)[q], id = ((const int*)&dA)[q];
        u32 bs = s_bm[(u32)is >> 5], bd = s_bm[(u32)id >> 5];
        mAi[q] = (int)((bs >> (is & 31)) & (bd >> (id & 31)) & 1u);
    }
    #pragma unroll
    for (int q = 0; q < 4; ++q) {
        int is = ((const int*)&sB)[q], id = ((const int*)&dB)[q];
        u32 bs = s_bm[(u32)is >> 5], bd = s_bm[(u32)id >> 5];
        mBi[q] = (int)((bs >> (is & 31)) & (bd >> (id & 31)) & 1u);
    }

    u16 vsA[4], vdA[4], vsB[4], vdB[4];
    #pragma unroll
    for (int q = 0; q < 4; ++q) {
        vsA[q] = table16[mAi[q] ? ((const int*)&sA)[q] : 0];
        vdA[q] = table16[mAi[q] ? ((const int*)&dA)[q] : 0];
    }
    #pragma unroll
    for (int q = 0; q < 4; ++q) {
        vsB[q] = table16[mBi[q] ? ((const int*)&sB)[q] : 0];
        vdB[q] = table16[mBi[q] ? ((const int*)&dB)[q] : 0];
    }

    // --- compute + stores (edge outputs) ---
    f32x4 rA, cA, oA, mA, rB, cB, oB, mB;
    #pragma unroll
    for (int q = 0; q < 4; ++q) {
        {
            int m = mAi[q];
            int r = ((((const int*)&sA)[q] >> 10) << 9) + (int)vsA[q];
            int c = ((((const int*)&dA)[q] >> 10) << 9) + (int)vdA[q];
            ((float*)&rA)[q] = m ? (float)r : -1.0f;
            ((float*)&cA)[q] = m ? (float)c : -1.0f;
            ((float*)&oA)[q] = m ? ((const float*)&aA)[q] : 0.0f;
            ((float*)&mA)[q] = (float)m;
        }
        {
            int m = mBi[q];
            int r = ((((const int*)&sB)[q] >> 10) << 9) + (int)vsB[q];
            int c = ((((const int*)&dB)[q] >> 10) << 9) + (int)vdB[q];
            ((float*)&rB)[q] = m ? (float)r : -1.0f;
            ((float*)&cB)[q] = m ? (float)c : -1.0f;
            ((float*)&oB)[q] = m ? ((const float*)&aB)[q] : 0.0f;
            ((float*)&mB)[q] = (float)m;
        }
    }

    __builtin_nontemporal_store(rA, &((f32x4*)ei0o)[i0]);
    __builtin_nontemporal_store(rB, &((f32x4*)ei0o)[i1]);
    __builtin_nontemporal_store(cA, &((f32x4*)ei1o)[i0]);
    __builtin_nontemporal_store(cB, &((f32x4*)ei1o)[i1]);
    __builtin_nontemporal_store(oA, &((f32x4*)eao)[i0]);
    __builtin_nontemporal_store(oB, &((f32x4*)eao)[i1]);
    __builtin_nontemporal_store(mA, &((f32x4*)msk)[i0]);
    __builtin_nontemporal_store(mB, &((f32x4*)msk)[i1]);

    // --- x_p stores ---
    #pragma unroll
    for (int p = 0; p < 4; ++p)
        __builtin_nontemporal_store(xv[p], &((f32x4*)xp)[gt + p * GTHREADS]);
}

extern "C" void kernel_launch(void* const* d_in, const int* in_sizes, int n_in,
                              void* d_out, int out_size, void* d_ws, size_t ws_size,
                              hipStream_t stream) {
    const float* x          = (const float*)d_in[0];
    const float* w          = (const float*)d_in[1];
    const float* bias       = (const float*)d_in[2];
    const int*   edge_index = (const int*)d_in[3];
    const float* edge_attr  = (const float*)d_in[4];
    const int*   batch      = (const int*)d_in[5];
    (void)batch;

    float* out = (float*)d_out;
    float* xp   = out + OFF_XP;
    float* ei0o = out + OFF_EI0;
    float* ei1o = out + OFF_EI1;
    float* eao  = out + OFF_EA;
    float* bpo  = out + OFF_BP;
    float* sco  = out + OFF_SC;
    float* pmo  = out + OFF_PM;
    float* msk  = out + OFF_MSK;

    u16* table16 = (u16*)d_ws;                                   // 512 KiB
    u16* src16   = (u16*)d_ws + BGRAPHS * NNODES;                // 256 KiB
    u32* bitmap  = (u32*)((char*)d_ws + (BGRAPHS * NNODES + BGRAPHS * KKEEP) * sizeof(u16)); // 32 KiB

    score_rank_kernel<<<BGRAPHS, 1024, 0, stream>>>(
        x, w, bias, sco, pmo, bpo, table16, src16, bitmap);
    edge_gather_kernel<<<FUSED_BLOCKS, 256, 0, stream>>>(
        edge_index, edge_attr, table16, bitmap, x, src16, ei0o, ei1o, eao, msk, xp);
}

// Round 6
// 216.136 us; speedup vs baseline: 1.1428x; 1.1428x over previous
//
#include <hip/hip_runtime.h>
#include <math.h>

#define BGRAPHS 256
#define NNODES  1024
#define CCH     64
#define NEDGE   4194304
#define KKEEP   512

typedef unsigned long long u64;
typedef unsigned int u32;
typedef unsigned short u16;
typedef float  f32x4 __attribute__((ext_vector_type(4)));
typedef int    i32x4 __attribute__((ext_vector_type(4)));

// Output layout (flat float32 elements)
#define OFF_XP   0
#define OFF_EI0  8388608
#define OFF_EI1  (8388608 + NEDGE)
#define OFF_EA   16777216
#define OFF_BP   20971520
#define OFF_SC   21102592
#define OFF_PM   21364736
#define OFF_MSK  21495808

#define FUSED_BLOCKS 2048       // 524288 threads: 8 edges + 4 xp-float4s each
#define GTHREADS     524288
#define BMWORDS      8192       // 256K nodes / 32 = 8192 u32 = 32 KB

// ------------- Kernel A: fused score + rank-by-counting top-k + bitmap -------------
// Score phase is now COALESCED: each wave streams its 64-node slab (16 KB)
// contiguously — lane l, iter i reads slab[i*64+l] (1 KB/wave-load, every
// line fully consumed once). Lane l holds w4[l&15]; shfl_xor over the
// 16-lane group reduces to the node dot. Fixes the 2.4x HBM over-fetch
// (153 MB -> ~68 MB) the strided per-thread pattern caused.
__device__ __forceinline__ u64 cmpex(u64 key, int j, bool dir, int lane) {
    u64 o = (u64)__shfl_xor((long long)key, j, 64);
    bool lower = ((lane & j) == 0);
    u64 mn = key < o ? key : o;
    u64 mx = key < o ? o : key;
    return (dir == lower) ? mn : mx;
}

__global__ __launch_bounds__(1024) void score_rank_kernel(
    const float* __restrict__ x, const float* __restrict__ w,
    const float* __restrict__ bias,
    float* __restrict__ sco, float* __restrict__ pmo, float* __restrict__ bpo,
    u16* __restrict__ table16, u16* __restrict__ src16,
    u32* __restrict__ bitmap)
{
    __shared__ float s_w[CCH];
    __shared__ float s_sc[NNODES];
    __shared__ u64 s_key[NNODES];
    __shared__ u32 s_bm[32];
    const int b = blockIdx.x;
    const int tid = threadIdx.x;
    const int lane = tid & 63;
    const int wid = tid >> 6;
    if (tid < CCH) s_w[tid] = w[tid];
    if (tid < 32) s_bm[tid] = 0u;
    __syncthreads();

    // ---- score phase (coalesced slab streaming + 16-lane reduce) ----
    double n2 = 0.0;
    #pragma unroll
    for (int k = 0; k < CCH; ++k) { double v = (double)s_w[k]; n2 += v * v; }
    const float nrm = (float)sqrt(n2);
    const float bv = bias[0];

    const f32x4 wv = *(const f32x4*)&s_w[(lane & 15) * 4];  // lane's channel quad
    // this wave's 64-node slab: float4 base
    const f32x4* slab = (const f32x4*)x + ((u64)((b << 10) + (wid << 6))) * 16;

    #pragma unroll
    for (int i = 0; i < 16; ++i) {
        f32x4 xv = slab[i * 64 + lane];
        double p = (double)xv.x * (double)wv.x + (double)xv.y * (double)wv.y
                 + (double)xv.z * (double)wv.z + (double)xv.w * (double)wv.w;
        // reduce the 16 lanes covering one node (xor within low-4 bits)
        p += __shfl_xor(p, 1, 64);
        p += __shfl_xor(p, 2, 64);
        p += __shfl_xor(p, 4, 64);
        p += __shfl_xor(p, 8, 64);
        if ((lane & 15) == 0)
            s_sc[(wid << 6) + (i << 2) + (lane >> 4)] = ((float)p + bv) / nrm;
    }
    // same-wave LDS readback (wave-synchronous; per-wave DS ops are in order)
    const float score = s_sc[tid];
    const int node = (b << 10) + tid;
    sco[node] = score;   // fully coalesced block-wide store

    // ---- rank phase (R3 core, unchanged) ----
    // key: descending score (primary), ascending index (secondary) -> ascending u64
    u32 u = __float_as_uint(score);
    u32 mu = u ^ (u32)(((int)u >> 31) | 0x80000000);
    u64 key = ((u64)(~mu) << 32) | (u32)tid;

    // in-wave bitonic sort: 64 keys ascending across the wave's lanes
    #pragma unroll
    for (int k = 2; k <= 64; k <<= 1) {
        bool dir = ((lane & k) == 0);
        for (int j = k >> 1; j > 0; j >>= 1)
            key = cmpex(key, j, dir, lane);
    }
    s_key[tid] = key;
    __syncthreads();

    // global rank: lane = count of smaller keys in own chunk (sorted, unique)
    const int mychunk = wid;           // wave-uniform
    int rank = lane;
    #pragma unroll
    for (int c = 0; c < 16; ++c) {
        if (c == mychunk) continue;    // wave-uniform branch
        const u64* base = &s_key[c << 6];
        int pos = 0;
        #pragma unroll
        for (int s = 32; s > 0; s >>= 1)
            pos += (base[pos + s - 1] < key) ? s : 0;
        pos += (base[pos] < key) ? 1 : 0;   // lower_bound in [0,64]
        rank += pos;
    }

    const int lidx = (int)(u32)key;
    const int g = (b << 10) + lidx;
    if (rank < KKEEP) {
        pmo[b * KKEEP + rank] = (float)g;
        bpo[b * KKEEP + rank] = (float)b;   // batch[g] == b by construction
        table16[g] = (u16)rank;             // local rank 0..511
        src16[b * KKEEP + rank] = (u16)lidx;
        atomicOr(&s_bm[lidx >> 5], 1u << (lidx & 31));
    }
    __syncthreads();
    if (tid < 32) bitmap[(b << 5) + tid] = s_bm[tid];
}

// ---------------- Kernel C: fused edge-filter + x_p gather ----------------
// Validity bitmap (32 KB) staged in LDS; table16 gathered ONLY for edges
// whose both endpoints survive (~25%) — masked lanes collapse to a single
// broadcast line (index 0). Cuts random L2 gather-lines ~4x.
__global__ __launch_bounds__(256) void edge_gather_kernel(
    const int* __restrict__ ei, const float* __restrict__ ea,
    const u16* __restrict__ table16, const u32* __restrict__ bitmap,
    const float* __restrict__ x, const u16* __restrict__ src16,
    float* __restrict__ ei0o, float* __restrict__ ei1o,
    float* __restrict__ eao, float* __restrict__ msk,
    float* __restrict__ xp)
{
    __shared__ u32 s_bm[BMWORDS];
    const int tid = threadIdx.x;
    const int gt = blockIdx.x * 256 + tid;      // 0..GTHREADS-1
    const int i0 = blockIdx.x * 512 + tid;      // int4 slot A (4 edges)
    const int i1 = i0 + 256;                    // int4 slot B

    // stage validity bitmap (32 KB) — coalesced, L2/L3-hot
    {
        const i32x4* bm4 = (const i32x4*)bitmap;
        i32x4* sb4 = (i32x4*)s_bm;
        #pragma unroll
        for (int i = 0; i < 8; ++i)
            sb4[tid + 256 * i] = bm4[tid + 256 * i];
    }

    const i32x4* s4p = (const i32x4*)ei;
    const i32x4* d4p = (const i32x4*)(ei + NEDGE);
    const f32x4* a4p = (const f32x4*)ea;
    const f32x4* x4  = (const f32x4*)x;

    // --- round 1: independent loads (6 edge streams + 4 src16) ---
    i32x4 sA = __builtin_nontemporal_load(&s4p[i0]);
    i32x4 sB = __builtin_nontemporal_load(&s4p[i1]);
    i32x4 dA = __builtin_nontemporal_load(&d4p[i0]);
    i32x4 dB = __builtin_nontemporal_load(&d4p[i1]);
    f32x4 aA = __builtin_nontemporal_load(&a4p[i0]);
    f32x4 aB = __builtin_nontemporal_load(&a4p[i1]);

    int rowv[4], colv[4], srcv[4];
    #pragma unroll
    for (int p = 0; p < 4; ++p) {
        int elem = gt + p * GTHREADS;
        rowv[p] = elem >> 4;
        colv[p] = elem & 15;
        srcv[p] = (int)src16[rowv[p]];    // 16 lanes share a row -> near-broadcast
    }

    // --- round 3 (moved up): x_p source rows, independent of edge data ---
    f32x4 xv[4];
    #pragma unroll
    for (int p = 0; p < 4; ++p) {
        int bb = rowv[p] >> 9;
        xv[p] = x4[((bb << 10) + srcv[p]) * 16 + colv[p]];
    }

    __syncthreads();   // bitmap ready

    // --- round 2: bitmap masks (LDS), then predicated table gathers ---
    int mAi[4], mBi[4];
    #pragma unroll
    for (int q = 0; q < 4; ++q) {
        int is = ((const int*)&sA)[q], id = ((const int*)&dA)[q];
        u32 bs = s_bm[(u32)is >> 5], bd = s_bm[(u32)id >> 5];
        mAi[q] = (int)((bs >> (is & 31)) & (bd >> (id & 31)) & 1u);
    }
    #pragma unroll
    for (int q = 0; q < 4; ++q) {
        int is = ((const int*)&sB)[q], id = ((const int*)&dB)[q];
        u32 bs = s_bm[(u32)is >> 5], bd = s_bm[(u32)id >> 5];
        mBi[q] = (int)((bs >> (is & 31)) & (bd >> (id & 31)) & 1u);
    }

    u16 vsA[4], vdA[4], vsB[4], vdB[4];
    #pragma unroll
    for (int q = 0; q < 4; ++q) {
        vsA[q] = table16[mAi[q] ? ((const int*)&sA)[q] : 0];
        vdA[q] = table16[mAi[q] ? ((const int*)&dA)[q] : 0];
    }
    #pragma unroll
    for (int q = 0; q < 4; ++q) {
        vsB[q] = table16[mBi[q] ? ((const int*)&sB)[q] : 0];
        vdB[q] = table16[mBi[q] ? ((const int*)&dB)[q] : 0];
    }

    // --- compute + stores (edge outputs) ---
    f32x4 rA, cA, oA, mA, rB, cB, oB, mB;
    #pragma unroll
    for (int q = 0; q < 4; ++q) {
        {
            int m = mAi[q];
            int r = ((((const int*)&sA)[q] >> 10) << 9) + (int)vsA[q];
            int c = ((((const int*)&dA)[q] >> 10) << 9) + (int)vdA[q];
            ((float*)&rA)[q] = m ? (float)r : -1.0f;
            ((float*)&cA)[q] = m ? (float)c : -1.0f;
            ((float*)&oA)[q] = m ? ((const float*)&aA)[q] : 0.0f;
            ((float*)&mA)[q] = (float)m;
        }
        {
            int m = mBi[q];
            int r = ((((const int*)&sB)[q] >> 10) << 9) + (int)vsB[q];
            int c = ((((const int*)&dB)[q] >> 10) << 9) + (int)vdB[q];
            ((float*)&rB)[q] = m ? (float)r : -1.0f;
            ((float*)&cB)[q] = m ? (float)c : -1.0f;
            ((float*)&oB)[q] = m ? ((const float*)&aB)[q] : 0.0f;
            ((float*)&mB)[q] = (float)m;
        }
    }

    __builtin_nontemporal_store(rA, &((f32x4*)ei0o)[i0]);
    __builtin_nontemporal_store(rB, &((f32x4*)ei0o)[i1]);
    __builtin_nontemporal_store(cA, &((f32x4*)ei1o)[i0]);
    __builtin_nontemporal_store(cB, &((f32x4*)ei1o)[i1]);
    __builtin_nontemporal_store(oA, &((f32x4*)eao)[i0]);
    __builtin_nontemporal_store(oB, &((f32x4*)eao)[i1]);
    __builtin_nontemporal_store(mA, &((f32x4*)msk)[i0]);
    __builtin_nontemporal_store(mB, &((f32x4*)msk)[i1]);

    // --- x_p stores ---
    #pragma unroll
    for (int p = 0; p < 4; ++p)
        __builtin_nontemporal_store(xv[p], &((f32x4*)xp)[gt + p * GTHREADS]);
}

extern "C" void kernel_launch(void* const* d_in, const int* in_sizes, int n_in,
                              void* d_out, int out_size, void* d_ws, size_t ws_size,
                              hipStream_t stream) {
    const float* x          = (const float*)d_in[0];
    const float* w          = (const float*)d_in[1];
    const float* bias       = (const float*)d_in[2];
    const int*   edge_index = (const int*)d_in[3];
    const float* edge_attr  = (const float*)d_in[4];
    const int*   batch      = (const int*)d_in[5];
    (void)batch;

    float* out = (float*)d_out;
    float* xp   = out + OFF_XP;
    float* ei0o = out + OFF_EI0;
    float* ei1o = out + OFF_EI1;
    float* eao  = out + OFF_EA;
    float* bpo  = out + OFF_BP;
    float* sco  = out + OFF_SC;
    float* pmo  = out + OFF_PM;
    float* msk  = out + OFF_MSK;

    u16* table16 = (u16*)d_ws;                                   // 512 KiB
    u16* src16   = (u16*)d_ws + BGRAPHS * NNODES;                // 256 KiB
    u32* bitmap  = (u32*)((char*)d_ws + (BGRAPHS * NNODES + BGRAPHS * KKEEP) * sizeof(u16)); // 32 KiB

    score_rank_kernel<<<BGRAPHS, 1024, 0, stream>>>(
        x, w, bias, sco, pmo, bpo, table16, src16, bitmap);
    edge_gather_kernel<<<FUSED_BLOCKS, 256, 0, stream>>>(
        edge_index, edge_attr, table16, bitmap, x, src16, ei0o, ei1o, eao, msk, xp);
}

// Round 7
// 213.554 us; speedup vs baseline: 1.1566x; 1.0121x over previous
//
#include <hip/hip_runtime.h>
#include <math.h>

#define BGRAPHS 256
#define NNODES  1024
#define CCH     64
#define NEDGE   4194304
#define KKEEP   512

typedef unsigned long long u64;
typedef unsigned int u32;
typedef unsigned short u16;
typedef float  f32x4 __attribute__((ext_vector_type(4)));
typedef int    i32x4 __attribute__((ext_vector_type(4)));

// Output layout (flat float32 elements)
#define OFF_XP   0
#define OFF_EI0  8388608
#define OFF_EI1  (8388608 + NEDGE)
#define OFF_EA   16777216
#define OFF_BP   20971520
#define OFF_SC   21102592
#define OFF_PM   21364736
#define OFF_MSK  21495808

#define EG_BLOCK   512          // 512-thread blocks: 4 blocks/CU x 8 waves = 32 waves (100%)
#define EG_BLOCKS  1024         // 524288 threads total: 8 edges + 4 xp-float4s each
#define GTHREADS   524288
#define BMWORDS    8192         // 256K nodes / 32 = 8192 u32 = 32 KB

// ------------- Kernel A: fused score + rank-by-counting top-k + bitmap -------------
// Score phase is COALESCED: each wave streams its 64-node slab (16 KB)
// contiguously — lane l, iter i reads slab[i*64+l] (1 KB/wave-load, every
// line fully consumed once). Lane l holds w4[l&15]; shfl_xor over the
// 16-lane group reduces to the node dot. (R6: fixed the 2.4x HBM over-fetch.)
__device__ __forceinline__ u64 cmpex(u64 key, int j, bool dir, int lane) {
    u64 o = (u64)__shfl_xor((long long)key, j, 64);
    bool lower = ((lane & j) == 0);
    u64 mn = key < o ? key : o;
    u64 mx = key < o ? o : key;
    return (dir == lower) ? mn : mx;
}

__global__ __launch_bounds__(1024) void score_rank_kernel(
    const float* __restrict__ x, const float* __restrict__ w,
    const float* __restrict__ bias,
    float* __restrict__ sco, float* __restrict__ pmo, float* __restrict__ bpo,
    u16* __restrict__ table16, u16* __restrict__ src16,
    u32* __restrict__ bitmap)
{
    __shared__ float s_w[CCH];
    __shared__ float s_sc[NNODES];
    __shared__ u64 s_key[NNODES];
    __shared__ u32 s_bm[32];
    const int b = blockIdx.x;
    const int tid = threadIdx.x;
    const int lane = tid & 63;
    const int wid = tid >> 6;
    if (tid < CCH) s_w[tid] = w[tid];
    if (tid < 32) s_bm[tid] = 0u;
    __syncthreads();

    // ---- score phase (coalesced slab streaming + 16-lane reduce) ----
    double n2 = 0.0;
    #pragma unroll
    for (int k = 0; k < CCH; ++k) { double v = (double)s_w[k]; n2 += v * v; }
    const float nrm = (float)sqrt(n2);
    const float bv = bias[0];

    const f32x4 wv = *(const f32x4*)&s_w[(lane & 15) * 4];  // lane's channel quad
    const f32x4* slab = (const f32x4*)x + ((u64)((b << 10) + (wid << 6))) * 16;

    #pragma unroll
    for (int i = 0; i < 16; ++i) {
        f32x4 xv = slab[i * 64 + lane];
        double p = (double)xv.x * (double)wv.x + (double)xv.y * (double)wv.y
                 + (double)xv.z * (double)wv.z + (double)xv.w * (double)wv.w;
        p += __shfl_xor(p, 1, 64);
        p += __shfl_xor(p, 2, 64);
        p += __shfl_xor(p, 4, 64);
        p += __shfl_xor(p, 8, 64);
        if ((lane & 15) == 0)
            s_sc[(wid << 6) + (i << 2) + (lane >> 4)] = ((float)p + bv) / nrm;
    }
    // same-wave LDS readback (wave-synchronous; per-wave DS ops are in order)
    const float score = s_sc[tid];
    const int node = (b << 10) + tid;
    sco[node] = score;   // fully coalesced block-wide store

    // ---- rank phase (R3 core, unchanged) ----
    u32 u = __float_as_uint(score);
    u32 mu = u ^ (u32)(((int)u >> 31) | 0x80000000);
    u64 key = ((u64)(~mu) << 32) | (u32)tid;

    #pragma unroll
    for (int k = 2; k <= 64; k <<= 1) {
        bool dir = ((lane & k) == 0);
        for (int j = k >> 1; j > 0; j >>= 1)
            key = cmpex(key, j, dir, lane);
    }
    s_key[tid] = key;
    __syncthreads();

    const int mychunk = wid;           // wave-uniform
    int rank = lane;
    #pragma unroll
    for (int c = 0; c < 16; ++c) {
        if (c == mychunk) continue;    // wave-uniform branch
        const u64* base = &s_key[c << 6];
        int pos = 0;
        #pragma unroll
        for (int s = 32; s > 0; s >>= 1)
            pos += (base[pos + s - 1] < key) ? s : 0;
        pos += (base[pos] < key) ? 1 : 0;   // lower_bound in [0,64]
        rank += pos;
    }

    const int lidx = (int)(u32)key;
    const int g = (b << 10) + lidx;
    if (rank < KKEEP) {
        pmo[b * KKEEP + rank] = (float)g;
        bpo[b * KKEEP + rank] = (float)b;   // batch[g] == b by construction
        table16[g] = (u16)rank;             // local rank 0..511
        src16[b * KKEEP + rank] = (u16)lidx;
        atomicOr(&s_bm[lidx >> 5], 1u << (lidx & 31));
    }
    __syncthreads();
    if (tid < 32) bitmap[(b << 5) + tid] = s_bm[tid];
}

// ---------------- Kernel C: fused edge-filter + x_p gather ----------------
// 512-thread blocks (R7): 4 blocks/CU x 8 waves = 32 waves/CU (100%) under
// the 32 KB LDS bitmap — 1.6x more in-flight gathers than 256-thread blocks
// (LDS capped those at 20 waves/CU), and half as many bitmap stagings.
__global__ __launch_bounds__(EG_BLOCK) void edge_gather_kernel(
    const int* __restrict__ ei, const float* __restrict__ ea,
    const u16* __restrict__ table16, const u32* __restrict__ bitmap,
    const float* __restrict__ x, const u16* __restrict__ src16,
    float* __restrict__ ei0o, float* __restrict__ ei1o,
    float* __restrict__ eao, float* __restrict__ msk,
    float* __restrict__ xp)
{
    __shared__ u32 s_bm[BMWORDS];
    const int tid = threadIdx.x;
    const int gt = blockIdx.x * EG_BLOCK + tid;      // 0..GTHREADS-1
    const int i0 = blockIdx.x * (2 * EG_BLOCK) + tid;  // int4 slot A (4 edges)
    const int i1 = i0 + EG_BLOCK;                      // int4 slot B

    // stage validity bitmap (32 KB) — coalesced, L2/L3-hot
    {
        const i32x4* bm4 = (const i32x4*)bitmap;
        i32x4* sb4 = (i32x4*)s_bm;
        #pragma unroll
        for (int i = 0; i < 4; ++i)
            sb4[tid + EG_BLOCK * i] = bm4[tid + EG_BLOCK * i];
    }

    const i32x4* s4p = (const i32x4*)ei;
    const i32x4* d4p = (const i32x4*)(ei + NEDGE);
    const f32x4* a4p = (const f32x4*)ea;
    const f32x4* x4  = (const f32x4*)x;

    // --- round 1: independent loads (6 edge streams + 4 src16) ---
    i32x4 sA = __builtin_nontemporal_load(&s4p[i0]);
    i32x4 sB = __builtin_nontemporal_load(&s4p[i1]);
    i32x4 dA = __builtin_nontemporal_load(&d4p[i0]);
    i32x4 dB = __builtin_nontemporal_load(&d4p[i1]);
    f32x4 aA = __builtin_nontemporal_load(&a4p[i0]);
    f32x4 aB = __builtin_nontemporal_load(&a4p[i1]);

    int rowv[4], colv[4], srcv[4];
    #pragma unroll
    for (int p = 0; p < 4; ++p) {
        int elem = gt + p * GTHREADS;
        rowv[p] = elem >> 4;
        colv[p] = elem & 15;
        srcv[p] = (int)src16[rowv[p]];    // 16 lanes share a row -> near-broadcast
    }

    // --- x_p source rows (independent of edge data) ---
    f32x4 xv[4];
    #pragma unroll
    for (int p = 0; p < 4; ++p) {
        int bb = rowv[p] >> 9;
        xv[p] = x4[((bb << 10) + srcv[p]) * 16 + colv[p]];
    }

    __syncthreads();   // bitmap ready

    // --- round 2: bitmap masks (LDS), then predicated table gathers ---
    int mAi[4], mBi[4];
    #pragma unroll
    for (int q = 0; q < 4; ++q) {
        int is = ((const int*)&sA)[q], id = ((const int*)&dA)[q];
        u32 bs = s_bm[(u32)is >> 5], bd = s_bm[(u32)id >> 5];
        mAi[q] = (int)((bs >> (is & 31)) & (bd >> (id & 31)) & 1u);
    }
    #pragma unroll
    for (int q = 0; q < 4; ++q) {
        int is = ((const int*)&sB)[q], id = ((const int*)&dB)[q];
        u32 bs = s_bm[(u32)is >> 5], bd = s_bm[(u32)id >> 5];
        mBi[q] = (int)((bs >> (is & 31)) & (bd >> (id & 31)) & 1u);
    }

    u16 vsA[4], vdA[4], vsB[4], vdB[4];
    #pragma unroll
    for (int q = 0; q < 4; ++q) {
        vsA[q] = table16[mAi[q] ? ((const int*)&sA)[q] : 0];
        vdA[q] = table16[mAi[q] ? ((const int*)&dA)[q] : 0];
    }
    #pragma unroll
    for (int q = 0; q < 4; ++q) {
        vsB[q] = table16[mBi[q] ? ((const int*)&sB)[q] : 0];
        vdB[q] = table16[mBi[q] ? ((const int*)&dB)[q] : 0];
    }

    // --- compute + stores (edge outputs) ---
    f32x4 rA, cA, oA, mA, rB, cB, oB, mB;
    #pragma unroll
    for (int q = 0; q < 4; ++q) {
        {
            int m = mAi[q];
            int r = ((((const int*)&sA)[q] >> 10) << 9) + (int)vsA[q];
            int c = ((((const int*)&dA)[q] >> 10) << 9) + (int)vdA[q];
            ((float*)&rA)[q] = m ? (float)r : -1.0f;
            ((float*)&cA)[q] = m ? (float)c : -1.0f;
            ((float*)&oA)[q] = m ? ((const float*)&aA)[q] : 0.0f;
            ((float*)&mA)[q] = (float)m;
        }
        {
            int m = mBi[q];
            int r = ((((const int*)&sB)[q] >> 10) << 9) + (int)vsB[q];
            int c = ((((const int*)&dB)[q] >> 10) << 9) + (int)vdB[q];
            ((float*)&rB)[q] = m ? (float)r : -1.0f;
            ((float*)&cB)[q] = m ? (float)c : -1.0f;
            ((float*)&oB)[q] = m ? ((const float*)&aB)[q] : 0.0f;
            ((float*)&mB)[q] = (float)m;
        }
    }

    __builtin_nontemporal_store(rA, &((f32x4*)ei0o)[i0]);
    __builtin_nontemporal_store(rB, &((f32x4*)ei0o)[i1]);
    __builtin_nontemporal_store(cA, &((f32x4*)ei1o)[i0]);
    __builtin_nontemporal_store(cB, &((f32x4*)ei1o)[i1]);
    __builtin_nontemporal_store(oA, &((f32x4*)eao)[i0]);
    __builtin_nontemporal_store(oB, &((f32x4*)eao)[i1]);
    __builtin_nontemporal_store(mA, &((f32x4*)msk)[i0]);
    __builtin_nontemporal_store(mB, &((f32x4*)msk)[i1]);

    // --- x_p stores ---
    #pragma unroll
    for (int p = 0; p < 4; ++p)
        __builtin_nontemporal_store(xv[p], &((f32x4*)xp)[gt + p * GTHREADS]);
}

extern "C" void kernel_launch(void* const* d_in, const int* in_sizes, int n_in,
                              void* d_out, int out_size, void* d_ws, size_t ws_size,
                              hipStream_t stream) {
    const float* x          = (const float*)d_in[0];
    const float* w          = (const float*)d_in[1];
    const float* bias       = (const float*)d_in[2];
    const int*   edge_index = (const int*)d_in[3];
    const float* edge_attr  = (const float*)d_in[4];
    const int*   batch      = (const int*)d_in[5];
    (void)batch;

    float* out = (float*)d_out;
    float* xp   = out + OFF_XP;
    float* ei0o = out + OFF_EI0;
    float* ei1o = out + OFF_EI1;
    float* eao  = out + OFF_EA;
    float* bpo  = out + OFF_BP;
    float* sco  = out + OFF_SC;
    float* pmo  = out + OFF_PM;
    float* msk  = out + OFF_MSK;

    u16* table16 = (u16*)d_ws;                                   // 512 KiB
    u16* src16   = (u16*)d_ws + BGRAPHS * NNODES;                // 256 KiB
    u32* bitmap  = (u32*)((char*)d_ws + (BGRAPHS * NNODES + BGRAPHS * KKEEP) * sizeof(u16)); // 32 KiB

    score_rank_kernel<<<BGRAPHS, 1024, 0, stream>>>(
        x, w, bias, sco, pmo, bpo, table16, src16, bitmap);
    edge_gather_kernel<<<EG_BLOCKS, EG_BLOCK, 0, stream>>>(
        edge_index, edge_attr, table16, bitmap, x, src16, ei0o, ei1o, eao, msk, xp);
}